// Round 1
// baseline (131.462 us; speedup 1.0000x reference)
//
#include <hip/hip_runtime.h>
#include <hip/hip_bf16.h>

// KAN harmonic-basis GEMM.
// out[b,h] = sum_{d,f} basis(x[b,d])[f] * W[d,f,h] + sum_d b[d,h]
// basis = [1, sin(x), cos(x), sin(2x), cos(2x), ..., sin(5x), cos(5x)]
//
// Split: f=0 term + bias -> exact fp32 per-h constant c[h].
//        f=1..10 terms  -> bf16 MFMA GEMM, M=16384, N=256, K=2560,
//        A generated on the fly from x, B = Wbt (bf16, prepped in d_ws).

#define BDIM 16384
#define DDIM 256
#define HOUT 256
#define KTOT 2560   // 256 d * 10 harmonic entries

#define BM 64
#define BN 128
#define LDA 40      // LDS row stride in bf16 elems (80 B: 16B-aligned, 2-way bank alias = free)
#define LDB 40

typedef __bf16 bf16x8 __attribute__((ext_vector_type(8)));
typedef float floatx4 __attribute__((ext_vector_type(4)));

__device__ __forceinline__ unsigned short f2bf(float f) {
    // round-to-nearest-even fp32 -> bf16 bits (inputs are finite)
    unsigned int u = __float_as_uint(f);
    return (unsigned short)((u + 0x7FFFu + ((u >> 16) & 1u)) >> 16);
}

// grid 2816 x 256:
//   blocks [0,2560): convert W[d][f=1..10][h] -> Wbt[h][k], k = dt*320 + hs*32 + dd
//   blocks [2560,2816): c[h] = sum_d (W[d][0][h] + bias[d][h])  (exact fp32)
__global__ void prep_kernel(const float* __restrict__ W, const float* __restrict__ bias,
                            unsigned short* __restrict__ Wbt, float* __restrict__ c) {
    const int bid = blockIdx.x;
    const int t = threadIdx.x;
    if (bid < 2560) {
        const int h = bid / 10;
        const int k = (bid - h * 10) * 256 + t;
        const int dt = k / 320;
        const int rem = k - dt * 320;
        const int hs = rem >> 5;    // harmonic step 0..9 (0=sin1,1=cos1,2=sin2,...)
        const int dd = rem & 31;
        const int d = dt * 32 + dd;
        const float w = W[(d * 11 + (hs + 1)) * 256 + h];
        Wbt[h * KTOT + k] = f2bf(w);
    } else {
        const int h = bid - 2560;
        __shared__ float red[256];
        red[t] = W[(t * 11) * 256 + h] + bias[t * 256 + h];
        __syncthreads();
        for (int s = 128; s > 0; s >>= 1) {
            if (t < s) red[t] += red[t + s];
            __syncthreads();
        }
        if (t == 0) c[h] = red[0];
    }
}

__global__ __launch_bounds__(256, 2)
void kan_gemm(const float* __restrict__ x, const unsigned short* __restrict__ Wbt,
              const float* __restrict__ c, float* __restrict__ out) {
    __shared__ unsigned short As[BM * LDA];   // 5120 B
    __shared__ unsigned short Bs[BN * LDB];   // 10240 B

    const int t = threadIdx.x;
    const int m0 = blockIdx.x * BM;
    const int h0 = blockIdx.y * BN;

    const int lane = t & 63;
    const int wave = t >> 6;
    const int wr = wave >> 1;       // wave row half (32 rows)
    const int wc = wave & 1;        // wave col half (64 cols)
    const int l15 = lane & 15;
    const int koff = lane >> 4;     // 0..3, k-group of 8

    // A-generation assignment: thread t -> row m_a, k-range q*8..q*8+7
    const int m_a = t & 63;
    const int q = t >> 6;

    // B-staging assignment: thread t -> row n_b, 32B chunk pair
    const int n_b = t >> 1;
    const int cpair = t & 1;

    floatx4 acc[2][4];
#pragma unroll
    for (int i = 0; i < 2; ++i)
#pragma unroll
        for (int j = 0; j < 4; ++j)
            acc[i][j] = (floatx4){0.f, 0.f, 0.f, 0.f};

    const float* xrow = x + (size_t)(m0 + m_a) * DDIM;
    const unsigned short* wrow = Wbt + (size_t)(h0 + n_b) * KTOT + cpair * 16;

    for (int dtile = 0; dtile < 8; ++dtile) {
        // x for this d-tile: 8 values per thread, held in registers for 10 harmonic steps
        float xv[8];
        {
            const float4 xa = *(const float4*)(xrow + dtile * 32 + q * 8);
            const float4 xb = *(const float4*)(xrow + dtile * 32 + q * 8 + 4);
            xv[0] = xa.x; xv[1] = xa.y; xv[2] = xa.z; xv[3] = xa.w;
            xv[4] = xb.x; xv[5] = xb.y; xv[6] = xb.z; xv[7] = xb.w;
        }
#pragma unroll
        for (int hs = 0; hs < 10; ++hs) {
            const int k0 = dtile * 320 + hs * 32;

            // B stage: issue global loads early (latency overlaps A-gen VALU)
            const int4* gb = (const int4*)(wrow + k0);
            int4 b0 = gb[0];
            int4 b1 = gb[1];

            // A gen: sin/cos of harmonic (hs>>1)+1; branch is wave-uniform
            const float mult = (float)((hs >> 1) + 1);
            union { unsigned short h[8]; int4 v; } av;
            if ((hs & 1) == 0) {
#pragma unroll
                for (int j = 0; j < 8; ++j) av.h[j] = f2bf(__sinf(xv[j] * mult));
            } else {
#pragma unroll
                for (int j = 0; j < 8; ++j) av.h[j] = f2bf(__cosf(xv[j] * mult));
            }
            *(int4*)(&As[m_a * LDA + q * 8]) = av.v;

            int4* bdst = (int4*)(&Bs[n_b * LDB + cpair * 16]);
            bdst[0] = b0;
            bdst[1] = b1;
            __syncthreads();

            bf16x8 afrag[2], bfrag[4];
#pragma unroll
            for (int i = 0; i < 2; ++i)
                afrag[i] = *(const bf16x8*)(&As[(wr * 32 + i * 16 + l15) * LDA + koff * 8]);
#pragma unroll
            for (int j = 0; j < 4; ++j)
                bfrag[j] = *(const bf16x8*)(&Bs[(wc * 64 + j * 16 + l15) * LDB + koff * 8]);
#pragma unroll
            for (int i = 0; i < 2; ++i)
#pragma unroll
                for (int j = 0; j < 4; ++j)
                    acc[i][j] = __builtin_amdgcn_mfma_f32_16x16x32_bf16(afrag[i], bfrag[j], acc[i][j], 0, 0, 0);
            __syncthreads();
        }
    }

    // epilogue: C/D layout col=lane&15, row=(lane>>4)*4+reg
    float cj[4];
#pragma unroll
    for (int j = 0; j < 4; ++j) cj[j] = c[h0 + wc * 64 + j * 16 + l15];
#pragma unroll
    for (int i = 0; i < 2; ++i) {
        const int row0 = m0 + wr * 32 + i * 16 + koff * 4;
#pragma unroll
        for (int j = 0; j < 4; ++j) {
            const int col = h0 + wc * 64 + j * 16 + l15;
#pragma unroll
            for (int r = 0; r < 4; ++r) {
                out[(size_t)(row0 + r) * HOUT + col] = acc[i][j][r] + cj[j];
            }
        }
    }
}

extern "C" void kernel_launch(void* const* d_in, const int* in_sizes, int n_in,
                              void* d_out, int out_size, void* d_ws, size_t ws_size,
                              hipStream_t stream) {
    const float* x = (const float*)d_in[0];
    const float* W = (const float*)d_in[1];
    const float* b = (const float*)d_in[2];
    float* out = (float*)d_out;

    unsigned short* Wbt = (unsigned short*)d_ws;                       // 2560*256 bf16 = 1,310,720 B
    float* c = (float*)((char*)d_ws + (size_t)KTOT * HOUT * 2);        // 256 fp32

    prep_kernel<<<2816, 256, 0, stream>>>(W, b, Wbt, c);
    kan_gemm<<<dim3(BDIM / BM, HOUT / BN), 256, 0, stream>>>(x, Wbt, c, out);
}

// Round 2
// 120.267 us; speedup vs baseline: 1.0931x; 1.0931x over previous
//
#include <hip/hip_runtime.h>
#include <hip/hip_bf16.h>

// KAN harmonic-basis GEMM, v2.
// out[b,h] = sum_{d,f} basis(x[b,d])[f] * W[d,f,h] + sum_d b[d,h]
// basis = [1, sin(x), cos(x), ..., sin(5x), cos(5x)]
//
// f=0 + bias -> fp32 partials c_part[8][256], summed in GEMM epilogue.
// f=1..10    -> bf16 MFMA GEMM, M=16384, N=256, K=2560.
//   A generated on the fly (sincos once + harmonic recurrence), staged in LDS
//   per 320-wide d-tile (one barrier pair per 80 MFMAs).
//   B = Wfrag in d_ws, pre-laid-out in MFMA B-fragment-linear order
//   [kt][n][dd] so each wave loads fragments directly from global (L2-hot,
//   1.3 MB total) -- no B LDS staging, no B bank conflicts.

#define BDIM 16384
#define DDIM 256
#define HOUT 256
#define KTOT 2560
#define NKT  80          // 2560 / 32 k-tiles
#define BM 64
#define BN 128
#define LDA_S 328        // As row stride in shorts: 164 words -> even bank spread

typedef __bf16 bf16x8 __attribute__((ext_vector_type(8)));
typedef float floatx4 __attribute__((ext_vector_type(4)));

__device__ __forceinline__ unsigned short f2bf(float f) {
    unsigned int u = __float_as_uint(f);
    return (unsigned short)((u + 0x7FFFu + ((u >> 16) & 1u)) >> 16);
}

__device__ __forceinline__ unsigned int pkbf(float a, float b) {
    __hip_bfloat162 r = __float22bfloat162_rn(make_float2(a, b));
    return *reinterpret_cast<unsigned int*>(&r);
}

// grid 88 x 256 threads.
// blocks [0,80): kt = bid; Wfrag[kt][n][dd] = bf16(W[dtile*32+dd][kt%10+1][n])
//   reads coalesced over n (t = n), writes 64 B contiguous per thread.
// blocks [80,88): p = bid-80; c_part[p][h] = sum_{d in p*32..+32} W[d][0][h] + b[d][h]
__global__ void prep_kernel(const float* __restrict__ W, const float* __restrict__ bias,
                            unsigned short* __restrict__ Wfrag, float* __restrict__ c_part) {
    const int bid = blockIdx.x;
    const int t = threadIdx.x;
    if (bid < NKT) {
        const int kt = bid;
        const int dtile = kt / 10;
        const int f = kt - dtile * 10 + 1;
        const float* wsrc = W + ((size_t)(dtile * 32) * 11 + f) * 256 + t;
        union { unsigned short s[32]; int4 v[4]; } buf;
#pragma unroll
        for (int dd = 0; dd < 32; ++dd)
            buf.s[dd] = f2bf(wsrc[(size_t)dd * 11 * 256]);
        int4* dst = (int4*)(Wfrag + ((size_t)kt * 256 + t) * 32);
#pragma unroll
        for (int v = 0; v < 4; ++v) dst[v] = buf.v[v];
    } else {
        const int p = bid - NKT;
        float acc = 0.f;
#pragma unroll
        for (int dd = 0; dd < 32; ++dd) {
            const int d = p * 32 + dd;
            acc += W[(size_t)(d * 11) * 256 + t] + bias[(size_t)d * 256 + t];
        }
        c_part[p * 256 + t] = acc;
    }
}

__global__ __launch_bounds__(256, 2)
void kan_gemm(const float* __restrict__ x, const unsigned short* __restrict__ Wfrag,
              const float* __restrict__ c_part, float* __restrict__ out) {
    __shared__ unsigned short As[BM * LDA_S];   // 41,984 B -> 2 blocks/CU

    const int t = threadIdx.x;
    const int m0 = blockIdx.x * BM;
    const int h0 = blockIdx.y * BN;

    const int lane = t & 63;
    const int wave = t >> 6;
    const int wr = wave >> 1;        // row half (32 rows)
    const int wc = wave & 1;         // col half (64 cols)
    const int l15 = lane & 15;
    const int koff = lane >> 4;      // 0..3

    // A-gen assignment: row = lane (64 rows), d-chunk of 8 = wave
    const int m_a = lane;
    const int q = wave;

    floatx4 acc[2][4];
#pragma unroll
    for (int i = 0; i < 2; ++i)
#pragma unroll
        for (int j = 0; j < 4; ++j)
            acc[i][j] = (floatx4){0.f, 0.f, 0.f, 0.f};

    const float* xrow = x + (size_t)(m0 + m_a) * DDIM;
    // B fragment base: addr(kt, j) = bbase + kt*8192 + j*512 shorts
    const unsigned short* bbase = Wfrag + (size_t)(h0 + wc * 64 + l15) * 32 + koff * 8;

    float4 xa = *(const float4*)(xrow + q * 8);
    float4 xb = *(const float4*)(xrow + q * 8 + 4);

    for (int dtile = 0; dtile < 8; ++dtile) {
        float xv[8] = {xa.x, xa.y, xa.z, xa.w, xb.x, xb.y, xb.z, xb.w};

        // A-gen: sincos once per x, harmonics 2..5 via angle addition.
        union { unsigned int u[4]; int4 v; } av[10];
#pragma unroll
        for (int p = 0; p < 4; ++p) {
            float sa, ca, sb, cb;
            __sincosf(xv[2 * p],     &sa, &ca);
            __sincosf(xv[2 * p + 1], &sb, &cb);
            float ska = sa, cka = ca, skb = sb, ckb = cb;
            av[0].u[p] = pkbf(ska, skb);
            av[1].u[p] = pkbf(cka, ckb);
#pragma unroll
            for (int k = 2; k <= 5; ++k) {
                const float nsa = ska * ca + cka * sa;
                const float nca = cka * ca - ska * sa;
                const float nsb = skb * cb + ckb * sb;
                const float ncb = ckb * cb - skb * sb;
                ska = nsa; cka = nca; skb = nsb; ckb = ncb;
                av[2 * k - 2].u[p] = pkbf(ska, skb);
                av[2 * k - 1].u[p] = pkbf(cka, ckb);
            }
        }
        unsigned short* arow = &As[m_a * LDA_S];
#pragma unroll
        for (int hs = 0; hs < 10; ++hs)
            *(int4*)(arow + hs * 32 + q * 8) = av[hs].v;

        __syncthreads();

        // prefetch next d-tile's x during MFMA phase
        if (dtile < 7) {
            xa = *(const float4*)(xrow + (dtile + 1) * 32 + q * 8);
            xb = *(const float4*)(xrow + (dtile + 1) * 32 + q * 8 + 4);
        }

#pragma unroll
        for (int hs = 0; hs < 10; ++hs) {
            const int kt = dtile * 10 + hs;
            bf16x8 bfrag[4];
#pragma unroll
            for (int j = 0; j < 4; ++j)
                bfrag[j] = *(const bf16x8*)(bbase + (size_t)kt * 8192 + j * 512);
            bf16x8 afrag[2];
#pragma unroll
            for (int i = 0; i < 2; ++i)
                afrag[i] = *(const bf16x8*)(&As[(wr * 32 + i * 16 + l15) * LDA_S + hs * 32 + koff * 8]);
#pragma unroll
            for (int i = 0; i < 2; ++i)
#pragma unroll
                for (int j = 0; j < 4; ++j)
                    acc[i][j] = __builtin_amdgcn_mfma_f32_16x16x32_bf16(afrag[i], bfrag[j], acc[i][j], 0, 0, 0);
        }
        __syncthreads();
    }

    // epilogue: C/D layout col=lane&15, row=(lane>>4)*4+reg; add c = sum of partials
    float cj[4];
#pragma unroll
    for (int j = 0; j < 4; ++j) {
        const int col = h0 + wc * 64 + j * 16 + l15;
        float s = 0.f;
#pragma unroll
        for (int p = 0; p < 8; ++p) s += c_part[p * 256 + col];
        cj[j] = s;
    }
#pragma unroll
    for (int i = 0; i < 2; ++i) {
        const int row0 = m0 + wr * 32 + i * 16 + koff * 4;
#pragma unroll
        for (int j = 0; j < 4; ++j) {
            const int col = h0 + wc * 64 + j * 16 + l15;
#pragma unroll
            for (int r = 0; r < 4; ++r)
                out[(size_t)(row0 + r) * HOUT + col] = acc[i][j][r] + cj[j];
        }
    }
}

extern "C" void kernel_launch(void* const* d_in, const int* in_sizes, int n_in,
                              void* d_out, int out_size, void* d_ws, size_t ws_size,
                              hipStream_t stream) {
    const float* x = (const float*)d_in[0];
    const float* W = (const float*)d_in[1];
    const float* b = (const float*)d_in[2];
    float* out = (float*)d_out;

    unsigned short* Wfrag = (unsigned short*)d_ws;                     // 80*256*32*2 = 1,310,720 B
    float* c_part = (float*)((char*)d_ws + (size_t)NKT * 256 * 32 * 2); // 8*256*4 = 8 KB

    prep_kernel<<<NKT + 8, 256, 0, stream>>>(W, b, Wfrag, c_part);
    kan_gemm<<<dim3(BDIM / BM, HOUT / BN), 256, 0, stream>>>(x, Wfrag, c_part, out);
}

// Round 3
// 117.044 us; speedup vs baseline: 1.1232x; 1.0275x over previous
//
#include <hip/hip_runtime.h>
#include <hip/hip_bf16.h>

// KAN harmonic-basis GEMM, v3.
// out[b,h] = sum_{d,f} basis(x[b,d])[f] * W[d,f,h] + sum_d b[d,h]
//
// f=0 + bias -> fp32 partials c_part[8][256], summed in GEMM epilogue.
// f=1..10    -> bf16 MFMA GEMM, M=16384, N=256, K=2560.
//   A generated on the fly (sincos once + Chebyshev harmonic recurrence),
//   written to LDS in MFMA-fragment-linear layout (conflict-free b128 r/w).
//   B = Wfrag (d_ws), fragment-linear in global; loads are 1KB-contiguous
//   per wave. Explicit double-buffered prefetch of both A (LDS) and B (L2)
//   fragments one k-step ahead to hide L2 latency.

#define BDIM 16384
#define DDIM 256
#define HOUT 256
#define KTOT 2560
#define NKT  80
#define BM 64
#define BN 128

typedef __bf16 bf16x8 __attribute__((ext_vector_type(8)));
typedef float floatx4 __attribute__((ext_vector_type(4)));

__device__ __forceinline__ unsigned short f2bf(float f) {
    unsigned int u = __float_as_uint(f);
    return (unsigned short)((u + 0x7FFFu + ((u >> 16) & 1u)) >> 16);
}

__device__ __forceinline__ unsigned int pkbf(float a, float b) {
    __hip_bfloat162 r = __float22bfloat162_rn(make_float2(a, b));
    return *reinterpret_cast<unsigned int*>(&r);
}

// grid 88 x 256 threads.
// blocks [0,80): kt = bid; Wfrag[kt][n][dd] = bf16(W[dtile*32+dd][kt%10+1][n])
// blocks [80,88): p = bid-80; c_part[p][h] = sum_{d in p*32..+32} W[d][0][h]+b[d][h]
__global__ void prep_kernel(const float* __restrict__ W, const float* __restrict__ bias,
                            unsigned short* __restrict__ Wfrag, float* __restrict__ c_part) {
    const int bid = blockIdx.x;
    const int t = threadIdx.x;
    if (bid < NKT) {
        const int kt = bid;
        const int dtile = kt / 10;
        const int f = kt - dtile * 10 + 1;
        const float* wsrc = W + ((size_t)(dtile * 32) * 11 + f) * 256 + t;
        union { unsigned short s[32]; int4 v[4]; } buf;
#pragma unroll
        for (int dd = 0; dd < 32; ++dd)
            buf.s[dd] = f2bf(wsrc[(size_t)dd * 11 * 256]);
        int4* dst = (int4*)(Wfrag + ((size_t)kt * 256 + t) * 32);
#pragma unroll
        for (int v = 0; v < 4; ++v) dst[v] = buf.v[v];
    } else {
        const int p = bid - NKT;
        float acc = 0.f;
#pragma unroll
        for (int dd = 0; dd < 32; ++dd) {
            const int d = p * 32 + dd;
            acc += W[(size_t)(d * 11) * 256 + t] + bias[(size_t)d * 256 + t];
        }
        c_part[p * 256 + t] = acc;
    }
}

// As layout: tile (hs, itile): base short offset (hs*4+itile)*512, lane slot lane*8.
// A wave's afrag read = 64 lanes x 16 B contiguous (1 KB). Gen writes are
// 16-lane-contiguous 256 B chunks. Both conflict-free.
__global__ __launch_bounds__(256, 2)
void kan_gemm(const float* __restrict__ x, const unsigned short* __restrict__ Wfrag,
              const float* __restrict__ c_part, float* __restrict__ out) {
    __shared__ unsigned short As[10 * 4 * 512];   // 40,960 B -> 2 blocks/CU

    const int t = threadIdx.x;
    const int m0 = blockIdx.x * BM;
    const int h0 = blockIdx.y * BN;

    const int lane = t & 63;
    const int wave = t >> 6;
    const int wr = wave >> 1;        // row half (32 rows)
    const int wc = wave & 1;         // col half (64 cols)
    const int l15 = lane & 15;
    const int koff = lane >> 4;

    // A-gen: row = lane, d-chunk of 8 = wave
    const int m_a = lane;
    const int q = wave;
    const int it_w = m_a >> 4;                    // which i-tile this thread's row is in
    const int slot = (m_a & 15) + 16 * q;         // lane slot within fragment tile

    floatx4 acc[2][4];
#pragma unroll
    for (int i = 0; i < 2; ++i)
#pragma unroll
        for (int j = 0; j < 4; ++j)
            acc[i][j] = (floatx4){0.f, 0.f, 0.f, 0.f};

    const float* xrow = x + (size_t)(m0 + m_a) * DDIM;
    const unsigned short* bbase = Wfrag + (size_t)(h0 + wc * 64 + l15) * 32 + koff * 8;

    float4 xa = *(const float4*)(xrow + q * 8);
    float4 xb = *(const float4*)(xrow + q * 8 + 4);

    for (int dtile = 0; dtile < 8; ++dtile) {
        // ---- A-gen: sincos once, Chebyshev for harmonics 2..5 ----
        float xv[8] = {xa.x, xa.y, xa.z, xa.w, xb.x, xb.y, xb.z, xb.w};
        float sc[8], cc[8], sp[8], cp[8], t2c[8];
#pragma unroll
        for (int j = 0; j < 8; ++j) {
            __sincosf(xv[j], &sc[j], &cc[j]);
            t2c[j] = cc[j] + cc[j];
            sp[j] = 0.f;
            cp[j] = 1.f;
        }
#pragma unroll
        for (int k = 1; k <= 5; ++k) {
            union { unsigned int u[4]; int4 v; } vs, vc;
#pragma unroll
            for (int p = 0; p < 4; ++p) {
                vs.u[p] = pkbf(sc[2 * p], sc[2 * p + 1]);
                vc.u[p] = pkbf(cc[2 * p], cc[2 * p + 1]);
            }
            *(int4*)(&As[((2 * k - 2) * 4 + it_w) * 512 + slot * 8]) = vs.v;
            *(int4*)(&As[((2 * k - 1) * 4 + it_w) * 512 + slot * 8]) = vc.v;
            if (k < 5) {
#pragma unroll
                for (int j = 0; j < 8; ++j) {
                    const float ns = t2c[j] * sc[j] - sp[j];
                    const float nc = t2c[j] * cc[j] - cp[j];
                    sp[j] = sc[j]; cp[j] = cc[j];
                    sc[j] = ns;   cc[j] = nc;
                }
            }
        }
        __syncthreads();

        // prefetch next d-tile's x during MFMA phase
        if (dtile < 7) {
            xa = *(const float4*)(xrow + (dtile + 1) * 32 + q * 8);
            xb = *(const float4*)(xrow + (dtile + 1) * 32 + q * 8 + 4);
        }

        // ---- MFMA loop, double-buffered A (LDS) and B (L2) fragments ----
        const unsigned short* bkt = bbase + (size_t)(dtile * 10) * 8192;

        bf16x8 bf0[4], bf1[4], af0[2], af1[2];
#pragma unroll
        for (int j = 0; j < 4; ++j)
            bf0[j] = *(const bf16x8*)(bkt + j * 512);
#pragma unroll
        for (int i = 0; i < 2; ++i)
            af0[i] = *(const bf16x8*)(&As[(0 * 4 + wr * 2 + i) * 512 + lane * 8]);

#pragma unroll
        for (int hs = 0; hs < 10; ++hs) {
            bf16x8* bnext = (hs & 1) ? bf0 : bf1;
            bf16x8* anext = (hs & 1) ? af0 : af1;
            if (hs < 9) {
#pragma unroll
                for (int j = 0; j < 4; ++j)
                    bnext[j] = *(const bf16x8*)(bkt + (size_t)(hs + 1) * 8192 + j * 512);
#pragma unroll
                for (int i = 0; i < 2; ++i)
                    anext[i] = *(const bf16x8*)(&As[((hs + 1) * 4 + wr * 2 + i) * 512 + lane * 8]);
            }
            const bf16x8* bcur = (hs & 1) ? bf1 : bf0;
            const bf16x8* acur = (hs & 1) ? af1 : af0;
#pragma unroll
            for (int i = 0; i < 2; ++i)
#pragma unroll
                for (int j = 0; j < 4; ++j)
                    acc[i][j] = __builtin_amdgcn_mfma_f32_16x16x32_bf16(acur[i], bcur[j], acc[i][j], 0, 0, 0);
        }
        __syncthreads();
    }

    // ---- epilogue: C/D layout col=lane&15, row=(lane>>4)*4+reg ----
    float cj[4];
#pragma unroll
    for (int j = 0; j < 4; ++j) {
        const int col = h0 + wc * 64 + j * 16 + l15;
        float s = 0.f;
#pragma unroll
        for (int p = 0; p < 8; ++p) s += c_part[p * 256 + col];
        cj[j] = s;
    }
#pragma unroll
    for (int i = 0; i < 2; ++i) {
        const int row0 = m0 + wr * 32 + i * 16 + koff * 4;
#pragma unroll
        for (int j = 0; j < 4; ++j) {
            const int col = h0 + wc * 64 + j * 16 + l15;
#pragma unroll
            for (int r = 0; r < 4; ++r)
                out[(size_t)(row0 + r) * HOUT + col] = acc[i][j][r] + cj[j];
        }
    }
}

extern "C" void kernel_launch(void* const* d_in, const int* in_sizes, int n_in,
                              void* d_out, int out_size, void* d_ws, size_t ws_size,
                              hipStream_t stream) {
    const float* x = (const float*)d_in[0];
    const float* W = (const float*)d_in[1];
    const float* b = (const float*)d_in[2];
    float* out = (float*)d_out;

    unsigned short* Wfrag = (unsigned short*)d_ws;                      // 1,310,720 B
    float* c_part = (float*)((char*)d_ws + (size_t)NKT * 256 * 32 * 2); // 8 KB

    prep_kernel<<<NKT + 8, 256, 0, stream>>>(W, b, Wfrag, c_part);
    kan_gemm<<<dim3(BDIM / BM, HOUT / BN), 256, 0, stream>>>(x, Wfrag, c_part, out);
}